// Round 9
// baseline (24.510 us; speedup 1.0000x reference)
//
#include <hip/hip_runtime.h>
#include <hip/hip_bf16.h>

#define VOCAB 32000
#define EDIM  128
#define QN    32
#define DN    256
#define NK    11

typedef __attribute__((ext_vector_type(8))) short bf16x8;
typedef __attribute__((ext_vector_type(4))) float f32x4;

#define EXP2F(x) __builtin_amdgcn_exp2f(x)

// ---- DPP 16-lane sum (within each aligned group of 16 lanes) ----
template <int CTRL>
static __device__ inline float dpp_add(float x) {
    int y = __builtin_amdgcn_update_dpp(0, __float_as_int(x), CTRL, 0xF, 0xF, true);
    return x + __int_as_float(y);
}
static __device__ inline float sum16(float x) {
    x = dpp_add<0xB1>(x);    // quad_perm xor 1
    x = dpp_add<0x4E>(x);    // quad_perm xor 2
    x = dpp_add<0x124>(x);   // row_ror:4
    x = dpp_add<0x128>(x);   // row_ror:8
    return x;
}

// XOR row swizzle: c = 16B-aligned byte column within a 256B (bf16) row
static __device__ inline int swz(int r, int c) { return c ^ ((r & 7) << 4); }

static __device__ inline bf16x8 pack8(float4 a, float4 b) {
    union { bf16x8 v; __hip_bfloat16 h[8]; } u;
    u.h[0] = __float2bfloat16(a.x); u.h[1] = __float2bfloat16(a.y);
    u.h[2] = __float2bfloat16(a.z); u.h[3] = __float2bfloat16(a.w);
    u.h[4] = __float2bfloat16(b.x); u.h[5] = __float2bfloat16(b.y);
    u.h[6] = __float2bfloat16(b.z); u.h[7] = __float2bfloat16(b.w);
    return u.v;
}
static __device__ inline float dot8(float4 a, float4 b) {
    float s = a.x * a.x + a.y * a.y + a.z * a.z + a.w * a.w;
    s = fmaf(b.x, b.x, s); s = fmaf(b.y, b.y, s);
    s = fmaf(b.z, b.z, s); s = fmaf(b.w, b.w, s);
    return s;
}

// ---------------- single fused kernel: one 8-wave block per batch ----------------
// VGPR capped at 128 (4 waves/EU) -> 2 blocks/CU guaranteed (LDS 74KB also = 2/CU).
__global__ __launch_bounds__(512, 4) void knrm_fused(const int* __restrict__ qtok,
                                                     const int* __restrict__ dtok,
                                                     const float* __restrict__ emb,
                                                     const float* __restrict__ fcw,
                                                     float* __restrict__ out) {
    __shared__ __align__(16) unsigned short dbuf[DN * EDIM];  // 64 KB
    __shared__ __align__(16) unsigned short qbuf[QN * EDIM];  // 8 KB; overlaid by part[8][16][NK]
    __shared__ int   dtokS[DN];
    __shared__ int   qtokS[QN];
    __shared__ float invS[DN + QN];                           // invd[0..255], invq[256..287]
    __shared__ float redS[8];

    const float INV_SQRT_2PI = 0.3989422804014327f;
    // chain constants c_m = exp(20*mu_m - 2)
    const float CCH[9] = {8886110.5f, 162754.797f, 2980.95799f, 54.5981500f, 1.0f,
                          0.0183156389f, 3.35462628e-4f, 6.14421235e-6f, 1.12535175e-7f};

    int b = blockIdx.x, tid = threadIdx.x;
    int w = tid >> 6, lane = tid & 63;
    int lr = lane & 15, lg = lane >> 4;

    if (tid < DN) dtokS[tid] = dtok[b * DN + tid];
    else if (tid < DN + QN) qtokS[tid - DN] = qtok[b * QN + (tid - DN)];
    __syncthreads();

    // ---- staging: 9 row-slots per wave (slot0 = q-row, slots1..8 = d-rows),
    //      3 chunks of 3 slots, next chunk's loads issued before processing current.
    //      Per-lane square-sums deferred; single DPP pass at the end.
    {
        float ss[9];
        float4 La[3][2], Lb[3][2];

        // slot -> unified row id (0..255 = d, 256+ = q) ; all compile-time unrolled
        #define ROWID(slot) ((slot) == 0 ? (DN + (w << 2) + lg) \
                                         : ((w << 5) + (((slot) - 1) << 2) + lg))
        #define TOKOF(rid)  ((rid) >= DN ? qtokS[(rid) - DN] : dtokS[(rid)])

        #define CHUNK_LOAD(Larr, c)                                              \
            _Pragma("unroll")                                                    \
            for (int s = 0; s < 3; ++s) {                                        \
                int rid = ROWID((c) * 3 + s);                                    \
                int tok = TOKOF(rid);                                            \
                const float4* src = (const float4*)(emb + (size_t)tok * EDIM) + lr * 2; \
                Larr[s][0] = src[0];                                             \
                Larr[s][1] = src[1];                                             \
            }

        #define CHUNK_PROC(Larr, c)                                              \
            _Pragma("unroll")                                                    \
            for (int s = 0; s < 3; ++s) {                                        \
                int slot = (c) * 3 + s;                                          \
                int rid = ROWID(slot);                                           \
                char* base = (rid >= DN) ? (char*)qbuf + (rid - DN) * 256        \
                                         : (char*)dbuf + rid * 256;              \
                *(bf16x8*)(base + swz(rid, lr * 16)) = pack8(Larr[s][0], Larr[s][1]); \
                ss[slot] = dot8(Larr[s][0], Larr[s][1]);                         \
            }

        CHUNK_LOAD(La, 0)
        CHUNK_LOAD(Lb, 1)
        CHUNK_PROC(La, 0)
        CHUNK_LOAD(La, 2)
        CHUNK_PROC(Lb, 1)
        CHUNK_PROC(La, 2)

        // deferred norms: 9 independent DPP chains, then one masked write each
        #pragma unroll
        for (int slot = 0; slot < 9; ++slot) {
            int rid = ROWID(slot);
            float tot = sum16(ss[slot]);
            if (lr == 0) invS[rid] = 1.0f / sqrtf(tot);
        }
        #undef CHUNK_LOAD
        #undef CHUNK_PROC
        #undef ROWID
        #undef TOKOF
    }
    __syncthreads();

    int qt = w & 1, ds = w >> 1;

    // ---- A fragments (raw q rows) + per-C-row inverse norms ----
    bf16x8 A0, A1, A2, A3;
    {
        int qr = (qt << 4) + lr;
        const char* qb = (const char*)qbuf + qr * 256;
        A0 = *(const bf16x8*)(qb + swz(qr, lg * 16));
        A1 = *(const bf16x8*)(qb + swz(qr, lg * 16 + 64));
        A2 = *(const bf16x8*)(qb + swz(qr, lg * 16 + 128));
        A3 = *(const bf16x8*)(qb + swz(qr, lg * 16 + 192));
    }
    int   qtr[4];
    float invq[4];
    #pragma unroll
    for (int r = 0; r < 4; ++r) {
        int qrow = (qt << 4) + (lg << 2) + r;
        qtr[r]  = qtokS[qrow];
        invq[r] = invS[DN + qrow];
    }
    __syncthreads();                                   // qbuf now free for overlay

    float* part = (float*)qbuf;                        // [8][16][NK] = 5.6 KB

    float kacc[4][NK];
    #pragma unroll
    for (int r = 0; r < 4; ++r)
        #pragma unroll
        for (int k = 0; k < NK; ++k) kacc[r][k] = 0.0f;

    // ---- eval loop with B-fragment prefetch depth 1 ----
    bf16x8 Bc0, Bc1, Bc2, Bc3;
    {
        int dr = (ds << 6) + lr;
        const char* db = (const char*)dbuf + dr * 256;
        Bc0 = *(const bf16x8*)(db + swz(dr, lg * 16));
        Bc1 = *(const bf16x8*)(db + swz(dr, lg * 16 + 64));
        Bc2 = *(const bf16x8*)(db + swz(dr, lg * 16 + 128));
        Bc3 = *(const bf16x8*)(db + swz(dr, lg * 16 + 192));
    }

    #pragma unroll
    for (int t = 0; t < 4; ++t) {
        int dr = (ds << 6) + (t << 4) + lr;
        int tcur = dtokS[dr];
        float invd = invS[dr];

        bf16x8 Bn0, Bn1, Bn2, Bn3;
        if (t < 3) {
            int drn = dr + 16;
            const char* db = (const char*)dbuf + drn * 256;
            Bn0 = *(const bf16x8*)(db + swz(drn, lg * 16));
            Bn1 = *(const bf16x8*)(db + swz(drn, lg * 16 + 64));
            Bn2 = *(const bf16x8*)(db + swz(drn, lg * 16 + 128));
            Bn3 = *(const bf16x8*)(db + swz(drn, lg * 16 + 192));
        }

        f32x4 acc = {0.0f, 0.0f, 0.0f, 0.0f};
        acc = __builtin_amdgcn_mfma_f32_16x16x32_bf16(A0, Bc0, acc, 0, 0, 0);
        acc = __builtin_amdgcn_mfma_f32_16x16x32_bf16(A1, Bc1, acc, 0, 0, 0);
        acc = __builtin_amdgcn_mfma_f32_16x16x32_bf16(A2, Bc2, acc, 0, 0, 0);
        acc = __builtin_amdgcn_mfma_f32_16x16x32_bf16(A3, Bc3, acc, 0, 0, 0);

        float sc = (tcur > 0) ? INV_SQRT_2PI : 0.0f;
        #pragma unroll
        for (int r = 0; r < 4; ++r) {
            float t2 = acc[r] * (invq[r] * invd);         // post-MFMA normalization
            kacc[r][0] += (tcur == qtr[r]) ? sc : 0.0f;   // K0: exact token match
            float s   = fabsf(t2);
            float scP = (t2 >= 0.0f) ? sc : 0.0f;
            float scN = sc - scP;
            float d   = s - 0.9f;
            float g   = EXP2F(d * d * -72.1347520f);      // exp(-50(s-0.9)^2)
            float E   = EXP2F(s * -28.8539008f);          // exp(-20s)
            #pragma unroll
            for (int m = 1; m <= 10; ++m) {
                kacc[r][m]      = fmaf(g, scP, kacc[r][m]);
                kacc[r][11 - m] = fmaf(g, scN, kacc[r][11 - m]);
                if (m < 10) g = g * E * CCH[m - 1];
            }
        }

        Bc0 = Bn0; Bc1 = Bn1; Bc2 = Bn2; Bc3 = Bn3;
    }

    // ---- DPP reduce over doc-columns; write wave partial [16][NK] ----
    #pragma unroll
    for (int r = 0; r < 4; ++r)
        #pragma unroll
        for (int k = 0; k < NK; ++k) kacc[r][k] = sum16(kacc[r][k]);

    if (lr == 0) {
        float* pw = part + w * (16 * NK) + (lg * 4) * NK;
        #pragma unroll
        for (int r = 0; r < 4; ++r)
            #pragma unroll
            for (int k = 0; k < NK; ++k)
                pw[r * NK + k] = kacc[r][k];
    }
    __syncthreads();

    // ---- combine 4 dspans, log-pool, weighted sum -> out[b] ----
    float total = 0.0f;
    if (tid < QN * NK) {
        int q = tid / NK, k = tid - (tid / NK) * NK;
        int qt2 = q >> 4, row = q & 15;
        const float* pb = part + qt2 * (16 * NK) + row * NK + k;
        float v = pb[0] + pb[2 * 16 * NK] + pb[4 * 16 * NK] + pb[6 * 16 * NK];
        float m = (qtokS[q] > 0) ? 1.0f : 0.0f;
        total = m * fcw[k] * __logf(fmaxf(v, 1e-10f));
    }
    #pragma unroll
    for (int off = 32; off; off >>= 1) total += __shfl_xor(total, off);
    if (lane == 0) redS[w] = total;
    __syncthreads();
    if (tid == 0) {
        float s = 0.0f;
        #pragma unroll
        for (int i = 0; i < 8; ++i) s += redS[i];
        out[b] = s;
    }
}

extern "C" void kernel_launch(void* const* d_in, const int* in_sizes, int n_in,
                              void* d_out, int out_size, void* d_ws, size_t ws_size,
                              hipStream_t stream) {
    const int*   qtok = (const int*)d_in[0];
    const int*   dtok = (const int*)d_in[1];
    const float* emb  = (const float*)d_in[2];
    const float* fcw  = (const float*)d_in[3];
    float* out = (float*)d_out;

    int B = in_sizes[0] / QN;                  // 512
    knrm_fused<<<B, 512, 0, stream>>>(qtok, dtok, emb, fcw, out);
}